// Round 18
// baseline (70.253 us; speedup 1.0000x reference)
//
#include <hip/hip_runtime.h>

#define CS   224
#define HH   1024
#define WW   1024
#define HW   (HH * WW)
#define RT   16              // rows per column tile
#define NTIL (HH / RT)       // 64
#define NCOLG 2              // 1024 cols / (256 threads * 2 floats)
#define ROWS 4               // output rows per gather block
#define S_FAST 449           // max s with ceil((223+s)/224) <= 3 (span fits dwordx4)
#define NXCD 8

typedef float f4u __attribute__((ext_vector_type(4), aligned(4)));

// ---- Pass 1: per-row inclusive cumsum into I (3072 blocks) -----------------
__global__ __launch_bounds__(256) void row_cumsum(
    const float* __restrict__ x, float* __restrict__ I)
{
    int row = blockIdx.x;                       // 0 .. 3*1024-1
    const float4* src = (const float4*)(x + (size_t)row * WW);
    float4*       dst = (float4*)(I + (size_t)row * WW);

    int t    = threadIdx.x;
    int lane = t & 63;
    int w    = t >> 6;

    float4 v = src[t];
    float s0 = v.x, s1 = s0 + v.y, s2 = s1 + v.z, s3 = s2 + v.w;
    float tsum = s3, sc = tsum;
    #pragma unroll
    for (int d = 1; d < 64; d <<= 1) {
        float o = __shfl_up(sc, d, 64);
        if (lane >= d) sc += o;
    }

    __shared__ float wsum[4];
    if (lane == 63) wsum[w] = sc;
    __syncthreads();
    float woff = 0.0f;
    #pragma unroll
    for (int k = 0; k < 4; ++k) woff += (k < w) ? wsum[k] : 0.0f;

    float ex = woff + sc - tsum;
    dst[t] = make_float4(ex + s0, ex + s1, ex + s2, ex + s3);
}

// ---- Pass 2: read-only tile column sums -> S -------------------------------
__global__ __launch_bounds__(256) void col_sum(
    const float* __restrict__ I, float* __restrict__ Sf)
{
    int b    = blockIdx.x;
    int tile = b % NTIL;
    int cg   = (b / NTIL) % NCOLG;
    int ch   = b / (NTIL * NCOLG);
    int c2   = cg * 256 + threadIdx.x;

    const float2* base = (const float2*)(I + (size_t)ch * HW
                                           + (size_t)(tile * RT) * WW) + c2;
    float2 acc = make_float2(0.0f, 0.0f);
    #pragma unroll
    for (int r = 0; r < RT; ++r) {
        float2 v = base[(size_t)r * (WW / 2)];
        acc.x += v.x; acc.y += v.y;
    }
    ((float2*)Sf)[(size_t)(ch * NTIL + tile) * (WW / 2) + c2] = acc;
}

// ---- Pass 3: inclusive scan of the 64 tile sums per column (wave/column) ---
__global__ __launch_bounds__(256) void scan_S(float* __restrict__ Sf)
{
    int gw   = (blockIdx.x * 256 + threadIdx.x) >> 6;   // global wave id
    int lane = threadIdx.x & 63;
    int c    = gw % WW;
    int ch   = gw / WW;

    size_t idx = ((size_t)(ch * NTIL + lane)) * WW + c;
    float v = Sf[idx];
    #pragma unroll
    for (int d = 1; d < 64; d <<= 1) {
        float o = __shfl_up(v, d, 64);
        if (lane >= d) v += o;
    }
    Sf[idx] = v;
}

// ---- Pass 4: fused within-tile cumsum + scanned offset (one I pass) --------
__global__ __launch_bounds__(256) void col_apply(
    float* __restrict__ I, const float* __restrict__ Sf)
{
    int b    = blockIdx.x;
    int tile = b % NTIL;
    int cg   = (b / NTIL) % NCOLG;
    int ch   = b / (NTIL * NCOLG);
    int c2   = cg * 256 + threadIdx.x;

    float2 acc = make_float2(0.0f, 0.0f);
    if (tile > 0)
        acc = ((const float2*)Sf)[(size_t)(ch * NTIL + tile - 1) * (WW / 2) + c2];

    float2* base = (float2*)(I + (size_t)ch * HW + (size_t)(tile * RT) * WW) + c2;
    #pragma unroll
    for (int r = 0; r < RT; ++r) {
        float2 v = base[(size_t)r * (WW / 2)];
        acc.x += v.x; acc.y += v.y;
        base[(size_t)r * (WW / 2)] = acc;
    }
}

__device__ __forceinline__ float extract4(f4u q, int k) {
    float r = q.x;
    r = (k == 1) ? q.y : r;
    r = (k == 2) ? q.z : r;
    r = (k == 3) ? q.w : r;
    return r;
}

// ---- Pass 5: gather (R15-proven) + XCD-bijective block swizzle -------------
// Swizzle gives each XCD an exclusive contiguous run of (ch,n) planes so each
// 4MB SAT plane is resident in exactly one XCD L2 (no 8x cross-XCD dup).
__global__ __launch_bounds__(256) void cutouts_gather(
    const float* __restrict__ I,
    const int*   __restrict__ sizesv,
    const int*   __restrict__ oyv,
    const int*   __restrict__ oxv,
    float*       __restrict__ out)
{
    // bijective XCD swizzle: nwg = 21504 = 8 * 2688
    int b0 = blockIdx.x;
    int b  = (b0 % NXCD) * (3 * 128 * (CS / ROWS) / NXCD) + b0 / NXCD;

    int rg  = b % (CS / ROWS);
    int rem = b / (CS / ROWS);
    int n   = rem % 128;
    int ch  = rem / 128;

    int j = threadIdx.x;
    if (j >= CS) return;

    int s   = sizesv[n];               // block-uniform -> scalar
    int oy_ = oyv[n];
    int ox_ = oxv[n];

    // per-lane column math, once for all ROWS rows
    int lo_j = (j * s) / CS;
    int hi_j = ((j + 1) * s + (CS - 1)) / CS;
    int c0   = ox_ + lo_j;
    int bcol = ox_ + hi_j - 1;                  // >= 0 always
    bool am  = (c0 > 0);
    int acol = am ? (c0 - 1) : 0;
    float rcpC = __builtin_amdgcn_rcpf((float)(hi_j - lo_j));

    const float* Ic = I + (size_t)ch * HW;

    // row-level values (block-uniform -> SALU)
    int  r1mv[ROWS], r0mv[ROWS];
    bool rmv[ROWS];
    float rcpA[ROWS];
    #pragma unroll
    for (int rr = 0; rr < ROWS; ++rr) {
        int i    = rg * ROWS + rr;
        int lo_i = (i * s) / CS;
        int nR   = ((i + 1) * s + (CS - 1)) / CS - lo_i;
        int r0   = oy_ + lo_i;
        r1mv[rr] = r0 + nR - 1;
        rmv[rr]  = (r0 > 0);
        r0mv[rr] = rmv[rr] ? (r0 - 1) : 0;
        rcpA[rr] = rcpC * __builtin_amdgcn_rcpf((float)nR);
    }

    if (s <= S_FAST) {
        // fast path: one dwordx4 per SAT row holds both taps (span <= 3)
        int basec = acol < (WW - 4) ? acol : (WW - 4);
        int oa = acol - basec;                   // 0..3
        int ob = bcol - basec;                   // 0..3

        f4u qh[ROWS], ql[ROWS];
        #pragma unroll
        for (int rr = 0; rr < ROWS; ++rr) {
            qh[rr] = *(const f4u*)(Ic + (size_t)r1mv[rr] * WW + basec);
            ql[rr] = *(const f4u*)(Ic + (size_t)r0mv[rr] * WW + basec);
        }
        #pragma unroll
        for (int rr = 0; rr < ROWS; ++rr) {
            int i = rg * ROWS + rr;
            float t11 = extract4(qh[rr], ob);
            float t10 = extract4(qh[rr], oa);
            float t01 = extract4(ql[rr], ob);
            float t00 = extract4(ql[rr], oa);
            float sum = (t11 - (am ? t10 : 0.0f))
                      - (rmv[rr] ? (t01 - (am ? t00 : 0.0f)) : 0.0f);
            out[((size_t)((n * 3 + ch) * CS) + i) * CS + j] = sum * rcpA[rr];
        }
    } else {
        // large-s path: 4 independent scalar taps (proven R11)
        float vhb[ROWS], vha[ROWS], vlb[ROWS], vla[ROWS];
        #pragma unroll
        for (int rr = 0; rr < ROWS; ++rr) {
            const float* Rhi = Ic + (size_t)r1mv[rr] * WW;
            const float* Rlo = Ic + (size_t)r0mv[rr] * WW;
            vhb[rr] = Rhi[bcol];
            vha[rr] = Rhi[acol];
            vlb[rr] = Rlo[bcol];
            vla[rr] = Rlo[acol];
        }
        #pragma unroll
        for (int rr = 0; rr < ROWS; ++rr) {
            int i = rg * ROWS + rr;
            float sum = vhb[rr]
                      - (am ? vha[rr] : 0.0f)
                      - (rmv[rr] ? vlb[rr] : 0.0f)
                      + ((am && rmv[rr]) ? vla[rr] : 0.0f);
            out[((size_t)((n * 3 + ch) * CS) + i) * CS + j] = sum * rcpA[rr];
        }
    }
}

extern "C" void kernel_launch(void* const* d_in, const int* in_sizes, int n_in,
                              void* d_out, int out_size, void* d_ws, size_t ws_size,
                              hipStream_t stream) {
    const float* x     = (const float*)d_in[0];
    const int*   sizes = (const int*)d_in[1];
    const int*   oy    = (const int*)d_in[2];
    const int*   ox    = (const int*)d_in[3];
    float*       out   = (float*)d_out;
    float*       I     = (float*)d_ws;               // 12 MB

    // Tile sums S (3*64*1024 floats = 768 KB) in the tail of d_out;
    // fully consumed by col_apply before the gather overwrites all of d_out.
    float* S = out + (out_size - 3 * NTIL * WW);

    row_cumsum<<<3 * HH, 256, 0, stream>>>(x, I);
    col_sum<<<3 * NCOLG * NTIL, 256, 0, stream>>>(I, S);
    scan_S<<<(3 * WW) / 4, 256, 0, stream>>>(S);       // 768 blocks
    col_apply<<<3 * NCOLG * NTIL, 256, 0, stream>>>(I, S);

    int blocks = 3 * 128 * (CS / ROWS);               // 21504
    cutouts_gather<<<blocks, 256, 0, stream>>>(I, sizes, oy, ox, out);
}

// Round 19
// 66.594 us; speedup vs baseline: 1.0549x; 1.0549x over previous
//
#include <hip/hip_runtime.h>

#define CS   224
#define HH   1024
#define WW   1024
#define HW   (HH * WW)
#define RT   16              // rows per column tile
#define NTIL (HH / RT)       // 64
#define NCOLG 2              // 1024 cols / (256 threads * 2 floats)
#define ROWS 4               // output rows per gather block
#define S_FAST 449           // max s with ceil((223+s)/224) <= 3 (span fits dwordx4)

typedef float f4u __attribute__((ext_vector_type(4), aligned(4)));

// ---- Pass 1: per-row inclusive cumsum into I (3072 blocks) -----------------
__global__ __launch_bounds__(256) void row_cumsum(
    const float* __restrict__ x, float* __restrict__ I)
{
    int row = blockIdx.x;                       // 0 .. 3*1024-1
    const float4* src = (const float4*)(x + (size_t)row * WW);
    float4*       dst = (float4*)(I + (size_t)row * WW);

    int t    = threadIdx.x;
    int lane = t & 63;
    int w    = t >> 6;

    float4 v = src[t];
    float s0 = v.x, s1 = s0 + v.y, s2 = s1 + v.z, s3 = s2 + v.w;
    float tsum = s3, sc = tsum;
    #pragma unroll
    for (int d = 1; d < 64; d <<= 1) {
        float o = __shfl_up(sc, d, 64);
        if (lane >= d) sc += o;
    }

    __shared__ float wsum[4];
    if (lane == 63) wsum[w] = sc;
    __syncthreads();
    float woff = 0.0f;
    #pragma unroll
    for (int k = 0; k < 4; ++k) woff += (k < w) ? wsum[k] : 0.0f;

    float ex = woff + sc - tsum;
    dst[t] = make_float4(ex + s0, ex + s1, ex + s2, ex + s3);
}

// ---- Pass 2: read-only tile column sums -> S -------------------------------
__global__ __launch_bounds__(256) void col_sum(
    const float* __restrict__ I, float* __restrict__ Sf)
{
    int b    = blockIdx.x;
    int tile = b % NTIL;
    int cg   = (b / NTIL) % NCOLG;
    int ch   = b / (NTIL * NCOLG);
    int c2   = cg * 256 + threadIdx.x;

    const float2* base = (const float2*)(I + (size_t)ch * HW
                                           + (size_t)(tile * RT) * WW) + c2;
    float2 acc = make_float2(0.0f, 0.0f);
    #pragma unroll
    for (int r = 0; r < RT; ++r) {
        float2 v = base[(size_t)r * (WW / 2)];
        acc.x += v.x; acc.y += v.y;
    }
    ((float2*)Sf)[(size_t)(ch * NTIL + tile) * (WW / 2) + c2] = acc;
}

// ---- Pass 3: inclusive scan of the 64 tile sums per column (wave/column) ---
__global__ __launch_bounds__(256) void scan_S(float* __restrict__ Sf)
{
    int gw   = (blockIdx.x * 256 + threadIdx.x) >> 6;   // global wave id
    int lane = threadIdx.x & 63;
    int c    = gw % WW;
    int ch   = gw / WW;

    size_t idx = ((size_t)(ch * NTIL + lane)) * WW + c;
    float v = Sf[idx];
    #pragma unroll
    for (int d = 1; d < 64; d <<= 1) {
        float o = __shfl_up(v, d, 64);
        if (lane >= d) v += o;
    }
    Sf[idx] = v;
}

// ---- Pass 4: fused within-tile cumsum + scanned offset (one I pass) --------
__global__ __launch_bounds__(256) void col_apply(
    float* __restrict__ I, const float* __restrict__ Sf)
{
    int b    = blockIdx.x;
    int tile = b % NTIL;
    int cg   = (b / NTIL) % NCOLG;
    int ch   = b / (NTIL * NCOLG);
    int c2   = cg * 256 + threadIdx.x;

    float2 acc = make_float2(0.0f, 0.0f);
    if (tile > 0)
        acc = ((const float2*)Sf)[(size_t)(ch * NTIL + tile - 1) * (WW / 2) + c2];

    float2* base = (float2*)(I + (size_t)ch * HW + (size_t)(tile * RT) * WW) + c2;
    #pragma unroll
    for (int r = 0; r < RT; ++r) {
        float2 v = base[(size_t)r * (WW / 2)];
        acc.x += v.x; acc.y += v.y;
        base[(size_t)r * (WW / 2)] = acc;
    }
}

__device__ __forceinline__ float extract4(f4u q, int k) {
    float r = q.x;
    r = (k == 1) ? q.y : r;
    r = (k == 2) ? q.z : r;
    r = (k == 3) ? q.w : r;
    return r;
}

// ---- Pass 5: gather. Block = 4 output rows of one (n,ch); lane = column. ---
// s <= 449 (block-uniform): span bcol-acol = nC <= 3, so ONE 4B-aligned
// dwordx4 per SAT row captures both taps -> 2 loads/output. Otherwise the
// proven 4x scalar-tap path (provably minimal for K0 >= 2).
__global__ __launch_bounds__(256) void cutouts_gather(
    const float* __restrict__ I,
    const int*   __restrict__ sizesv,
    const int*   __restrict__ oyv,
    const int*   __restrict__ oxv,
    float*       __restrict__ out)
{
    int b   = blockIdx.x;              // ((ch*128)+n)*56 + rg
    int rg  = b % (CS / ROWS);
    int rem = b / (CS / ROWS);
    int n   = rem % 128;
    int ch  = rem / 128;               // slowest: working set = one 4MB plane

    int j = threadIdx.x;
    if (j >= CS) return;

    int s   = sizesv[n];               // block-uniform -> scalar
    int oy_ = oyv[n];
    int ox_ = oxv[n];

    // per-lane column math, once for all ROWS rows
    int lo_j = (j * s) / CS;
    int hi_j = ((j + 1) * s + (CS - 1)) / CS;
    int c0   = ox_ + lo_j;
    int bcol = ox_ + hi_j - 1;                  // >= 0 always
    bool am  = (c0 > 0);
    int acol = am ? (c0 - 1) : 0;
    float rcpC = __builtin_amdgcn_rcpf((float)(hi_j - lo_j));

    const float* Ic = I + (size_t)ch * HW;

    // row-level values (block-uniform -> SALU)
    int  r1mv[ROWS], r0mv[ROWS];
    bool rmv[ROWS];
    float rcpA[ROWS];
    #pragma unroll
    for (int rr = 0; rr < ROWS; ++rr) {
        int i    = rg * ROWS + rr;
        int lo_i = (i * s) / CS;
        int nR   = ((i + 1) * s + (CS - 1)) / CS - lo_i;
        int r0   = oy_ + lo_i;
        r1mv[rr] = r0 + nR - 1;
        rmv[rr]  = (r0 > 0);
        r0mv[rr] = rmv[rr] ? (r0 - 1) : 0;
        rcpA[rr] = rcpC * __builtin_amdgcn_rcpf((float)nR);
    }

    if (s <= S_FAST) {
        // fast path: one dwordx4 per SAT row holds both taps (span <= 3)
        int basec = acol < (WW - 4) ? acol : (WW - 4);
        int oa = acol - basec;                   // 0..3
        int ob = bcol - basec;                   // 0..3

        f4u qh[ROWS], ql[ROWS];
        #pragma unroll
        for (int rr = 0; rr < ROWS; ++rr) {
            qh[rr] = *(const f4u*)(Ic + (size_t)r1mv[rr] * WW + basec);
            ql[rr] = *(const f4u*)(Ic + (size_t)r0mv[rr] * WW + basec);
        }
        #pragma unroll
        for (int rr = 0; rr < ROWS; ++rr) {
            int i = rg * ROWS + rr;
            float t11 = extract4(qh[rr], ob);
            float t10 = extract4(qh[rr], oa);
            float t01 = extract4(ql[rr], ob);
            float t00 = extract4(ql[rr], oa);
            float sum = (t11 - (am ? t10 : 0.0f))
                      - (rmv[rr] ? (t01 - (am ? t00 : 0.0f)) : 0.0f);
            out[((size_t)((n * 3 + ch) * CS) + i) * CS + j] = sum * rcpA[rr];
        }
    } else {
        // large-s path: 4 independent scalar taps (proven R11)
        float vhb[ROWS], vha[ROWS], vlb[ROWS], vla[ROWS];
        #pragma unroll
        for (int rr = 0; rr < ROWS; ++rr) {
            const float* Rhi = Ic + (size_t)r1mv[rr] * WW;
            const float* Rlo = Ic + (size_t)r0mv[rr] * WW;
            vhb[rr] = Rhi[bcol];
            vha[rr] = Rhi[acol];
            vlb[rr] = Rlo[bcol];
            vla[rr] = Rlo[acol];
        }
        #pragma unroll
        for (int rr = 0; rr < ROWS; ++rr) {
            int i = rg * ROWS + rr;
            float sum = vhb[rr]
                      - (am ? vha[rr] : 0.0f)
                      - (rmv[rr] ? vlb[rr] : 0.0f)
                      + ((am && rmv[rr]) ? vla[rr] : 0.0f);
            out[((size_t)((n * 3 + ch) * CS) + i) * CS + j] = sum * rcpA[rr];
        }
    }
}

extern "C" void kernel_launch(void* const* d_in, const int* in_sizes, int n_in,
                              void* d_out, int out_size, void* d_ws, size_t ws_size,
                              hipStream_t stream) {
    const float* x     = (const float*)d_in[0];
    const int*   sizes = (const int*)d_in[1];
    const int*   oy    = (const int*)d_in[2];
    const int*   ox    = (const int*)d_in[3];
    float*       out   = (float*)d_out;
    float*       I     = (float*)d_ws;               // 12 MB

    // Tile sums S (3*64*1024 floats = 768 KB) in the tail of d_out;
    // fully consumed by col_apply before the gather overwrites all of d_out.
    float* S = out + (out_size - 3 * NTIL * WW);

    row_cumsum<<<3 * HH, 256, 0, stream>>>(x, I);
    col_sum<<<3 * NCOLG * NTIL, 256, 0, stream>>>(I, S);
    scan_S<<<(3 * WW) / 4, 256, 0, stream>>>(S);       // 768 blocks
    col_apply<<<3 * NCOLG * NTIL, 256, 0, stream>>>(I, S);

    int blocks = 3 * 128 * (CS / ROWS);               // 21504
    cutouts_gather<<<blocks, 256, 0, stream>>>(I, sizes, oy, ox, out);
}

// Round 20
// 56.491 us; speedup vs baseline: 1.2436x; 1.1789x over previous
//
#include <hip/hip_runtime.h>

#define CS   224
#define HH   1024
#define WW   1024
#define HW   (HH * WW)
#define RT   16              // rows per column tile
#define NTIL (HH / RT)       // 64
#define NCOLG 2              // 1024 cols / (256 threads * 2 floats)
#define ROWS 4               // output rows per gather block

typedef float f4u __attribute__((ext_vector_type(4), aligned(4)));
typedef float f2u __attribute__((ext_vector_type(2), aligned(4)));

// ---- Pass 1: read-only tile column sums of x -> S ---------------------------
__global__ __launch_bounds__(256) void col_sum(
    const float* __restrict__ x, float* __restrict__ Sf)
{
    int b    = blockIdx.x;
    int tile = b % NTIL;
    int cg   = (b / NTIL) % NCOLG;
    int ch   = b / (NTIL * NCOLG);
    int c2   = cg * 256 + threadIdx.x;

    const float2* base = (const float2*)(x + (size_t)ch * HW
                                           + (size_t)(tile * RT) * WW) + c2;
    float2 acc = make_float2(0.0f, 0.0f);
    #pragma unroll
    for (int r = 0; r < RT; ++r) {
        float2 v = base[(size_t)r * (WW / 2)];
        acc.x += v.x; acc.y += v.y;
    }
    ((float2*)Sf)[(size_t)(ch * NTIL + tile) * (WW / 2) + c2] = acc;
}

// ---- Pass 2: inclusive scan of the 64 tile sums per column (wave/column) ---
__global__ __launch_bounds__(256) void scan_S(float* __restrict__ Sf)
{
    int gw   = (blockIdx.x * 256 + threadIdx.x) >> 6;   // global wave id
    int lane = threadIdx.x & 63;
    int c    = gw % WW;
    int ch   = gw / WW;

    size_t idx = ((size_t)(ch * NTIL + lane)) * WW + c;
    float v = Sf[idx];
    #pragma unroll
    for (int d = 1; d < 64; d <<= 1) {
        float o = __shfl_up(v, d, 64);
        if (lane >= d) v += o;
    }
    Sf[idx] = v;
}

// ---- Pass 3: fused within-tile column cumsum + scanned offset: x -> V ------
__global__ __launch_bounds__(256) void col_apply(
    const float* __restrict__ x, const float* __restrict__ Sf,
    float* __restrict__ V)
{
    int b    = blockIdx.x;
    int tile = b % NTIL;
    int cg   = (b / NTIL) % NCOLG;
    int ch   = b / (NTIL * NCOLG);
    int c2   = cg * 256 + threadIdx.x;

    float2 acc = make_float2(0.0f, 0.0f);
    if (tile > 0)
        acc = ((const float2*)Sf)[(size_t)(ch * NTIL + tile - 1) * (WW / 2) + c2];

    const float2* src = (const float2*)(x + (size_t)ch * HW
                                          + (size_t)(tile * RT) * WW) + c2;
    float2*       dst = (float2*)(V + (size_t)ch * HW
                                    + (size_t)(tile * RT) * WW) + c2;
    #pragma unroll
    for (int r = 0; r < RT; ++r) {
        float2 v = src[(size_t)r * (WW / 2)];
        acc.x += v.x; acc.y += v.y;
        dst[(size_t)r * (WW / 2)] = acc;
    }
}

// ---- Pass 4: gather from column-SAT. Contiguous horizontal window. ---------
// out(i,j) = sum_{c in [c0, c0+nC)} (V[r1m][c] - V[r0m][c]) / (nR*nC).
// nC <= K0+2 (K0 = floor(s/224), block-uniform): K0<=2 -> ONE dwordx4 per
// row level; K0=3 -> +scalar; K0=4 -> +dwordx2. No left tap, no masks
// except the top-row rm. All extraction is named-vector ternaries.
template<int K0>
__device__ __forceinline__ void gather_impl(
    const float* __restrict__ Vc, int s, int oy_, int ox_,
    int rg, int j, float* __restrict__ ob)
{
    int lo_j = (j * s) / CS;
    int hi_j = ((j + 1) * s + CS - 1) / CS;
    int nC   = hi_j - lo_j;                    // in [K0, K0+2]
    int c0   = ox_ + lo_j;
    float rcpC = __builtin_amdgcn_rcpf((float)nC);

    #pragma unroll
    for (int rr = 0; rr < ROWS; ++rr) {
        int i    = rg * ROWS + rr;
        int lo_i = (i * s) / CS;
        int nR   = ((i + 1) * s + CS - 1) / CS - lo_i;
        int r0   = oy_ + lo_i;
        int r1m  = r0 + nR - 1;
        bool rm  = (r0 > 0);
        int r0m  = rm ? (r0 - 1) : 0;

        const float* Rhi = Vc + (size_t)r1m * WW + c0;
        const float* Rlo = Vc + (size_t)r0m * WW + c0;

        f4u qh = *(const f4u*)Rhi;
        f4u ql = *(const f4u*)Rlo;
        float sh, sl;
        if constexpr (K0 == 1) {
            sh = qh.x + (nC >= 2 ? qh.y : 0.0f) + (nC >= 3 ? qh.z : 0.0f);
            sl = ql.x + (nC >= 2 ? ql.y : 0.0f) + (nC >= 3 ? ql.z : 0.0f);
        } else if constexpr (K0 == 2) {
            sh = qh.x + qh.y + (nC >= 3 ? qh.z : 0.0f) + (nC >= 4 ? qh.w : 0.0f);
            sl = ql.x + ql.y + (nC >= 3 ? ql.z : 0.0f) + (nC >= 4 ? ql.w : 0.0f);
        } else if constexpr (K0 == 3) {
            float eh = Rhi[4], el = Rlo[4];
            sh = qh.x + qh.y + qh.z + (nC >= 4 ? qh.w : 0.0f) + (nC >= 5 ? eh : 0.0f);
            sl = ql.x + ql.y + ql.z + (nC >= 4 ? ql.w : 0.0f) + (nC >= 5 ? el : 0.0f);
        } else {
            f2u eh = *(const f2u*)(Rhi + 4);
            f2u el = *(const f2u*)(Rlo + 4);
            sh = qh.x + qh.y + qh.z + qh.w + (nC >= 5 ? eh.x : 0.0f) + (nC >= 6 ? eh.y : 0.0f);
            sl = ql.x + ql.y + ql.z + ql.w + (nC >= 5 ? el.x : 0.0f) + (nC >= 6 ? el.y : 0.0f);
        }

        float sum  = sh - (rm ? sl : 0.0f);
        float rcpR = __builtin_amdgcn_rcpf((float)nR);
        ob[(size_t)i * CS + j] = sum * (rcpC * rcpR);
    }
}

__global__ __launch_bounds__(256) void cutouts_gather(
    const float* __restrict__ V,
    const int*   __restrict__ sizesv,
    const int*   __restrict__ oyv,
    const int*   __restrict__ oxv,
    float*       __restrict__ out)
{
    int b   = blockIdx.x;              // ((ch*128)+n)*56 + rg
    int rg  = b % (CS / ROWS);
    int rem = b / (CS / ROWS);
    int n   = rem % 128;
    int ch  = rem / 128;               // slowest: working set = one 4MB plane

    int j = threadIdx.x;
    if (j >= CS) return;

    int s   = sizesv[n];               // block-uniform -> scalar
    int oy_ = oyv[n];
    int ox_ = oxv[n];

    const float* Vc = V + (size_t)ch * HW;
    float* ob = out + (size_t)((n * 3 + ch) * CS) * CS;

    int k0 = s / CS;                   // 1..4, block-uniform
    if      (k0 == 1) gather_impl<1>(Vc, s, oy_, ox_, rg, j, ob);
    else if (k0 == 2) gather_impl<2>(Vc, s, oy_, ox_, rg, j, ob);
    else if (k0 == 3) gather_impl<3>(Vc, s, oy_, ox_, rg, j, ob);
    else              gather_impl<4>(Vc, s, oy_, ox_, rg, j, ob);
}

extern "C" void kernel_launch(void* const* d_in, const int* in_sizes, int n_in,
                              void* d_out, int out_size, void* d_ws, size_t ws_size,
                              hipStream_t stream) {
    const float* x     = (const float*)d_in[0];
    const int*   sizes = (const int*)d_in[1];
    const int*   oy    = (const int*)d_in[2];
    const int*   ox    = (const int*)d_in[3];
    float*       out   = (float*)d_out;
    float*       V     = (float*)d_ws;               // 12 MB column-SAT

    // Tile sums S (3*64*1024 floats = 768 KB) in the tail of d_out;
    // fully consumed by col_apply before the gather overwrites all of d_out.
    float* S = out + (out_size - 3 * NTIL * WW);

    col_sum<<<3 * NCOLG * NTIL, 256, 0, stream>>>(x, S);
    scan_S<<<(3 * WW) / 4, 256, 0, stream>>>(S);       // 768 blocks
    col_apply<<<3 * NCOLG * NTIL, 256, 0, stream>>>(x, S, V);

    int blocks = 3 * 128 * (CS / ROWS);               // 21504
    cutouts_gather<<<blocks, 256, 0, stream>>>(V, sizes, oy, ox, out);
}